// Round 1
// baseline (3133.718 us; speedup 1.0000x reference)
//
#include <hip/hip_runtime.h>
#include <math.h>

#define Bn 128
#define Tn 256
#define Fn 36
#define Hn 128
#define F2n 72
#define G4 512
#define BTFn (Bn*Tn*Fn)

// workspace layout (floats)
#define INVD_OFF 0
#define WIHT_OFF 256
#define WHHT_OFF (WIHT_OFF + F2n*G4)          // 256 + 36864 = 37120
#define LOSS_OFF (WHHT_OFF + Hn*G4)           // 37120 + 65536 = 102656
#define IMP_OFF  (LOSS_OFF + 384)             // 103040 ; + 3*BTFn = 3641984 floats (~14.6 MB)

__device__ __forceinline__ float sigmoid_f(float x) {
    return __builtin_amdgcn_rcpf(1.f + __expf(-x));
}
__device__ __forceinline__ float tanh_f(float x) {
    return fmaf(2.f, __builtin_amdgcn_rcpf(1.f + __expf(-2.f * x)), -1.f);
}

// ---------------- prep: inv-denom per t, transpose gate weights ----------------
__global__ void prep_kernel(const float* __restrict__ data,
                            const float* __restrict__ W_ih,
                            const float* __restrict__ W_hh,
                            float* __restrict__ ws) {
    int t = blockIdx.x;          // 0..255
    int tid = threadIdx.x;
    __shared__ float red[256];
    float s = 0.f;
    for (int idx = tid; idx < Bn * Fn; idx += 256) {
        int b = idx / Fn, f = idx - b * Fn;
        s += data[((size_t)(b * 24 + 1) * Tn + t) * Fn + f];
    }
    red[tid] = s;
    __syncthreads();
    for (int off = 128; off > 0; off >>= 1) {
        if (tid < off) red[tid] += red[tid + off];
        __syncthreads();
    }
    if (tid == 0) ws[INVD_OFF + t] = 1.f / (red[0] + 1e-5f);

    // W_ihT: (72,512) from W_ih (512,72). 36864 elems / 256 blocks = 144 each.
    for (int i = tid; i < 144; i += 256) {
        int o = t * 144 + i;                 // o = kk*512 + j
        ws[WIHT_OFF + o] = W_ih[(o & 511) * F2n + (o >> 9)];
    }
    // W_hhT: (128,512) from W_hh (512,128). 65536 / 256 = 256 each.
    {
        int o = t * 256 + tid;
        ws[WHHT_OFF + o] = W_hh[(o & 511) * Hn + (o >> 9)];
    }
}

// ---------------- main: one block per (b,k) chain ----------------
__global__ __launch_bounds__(256, 2) void rits_main(
    const float* __restrict__ data,
    const float* __restrict__ W_dh, const float* __restrict__ b_dh,
    const float* __restrict__ W_dx, const float* __restrict__ b_dx,
    const float* __restrict__ W_hist, const float* __restrict__ b_hist,
    const float* __restrict__ W_feat, const float* __restrict__ b_feat,
    const float* __restrict__ W_wc, const float* __restrict__ b_wc,
    const float* __restrict__ b_ih, const float* __restrict__ b_hh,
    const float* __restrict__ W_comb,
    float* __restrict__ ws) {

    const float* wihT = ws + WIHT_OFF;
    const float* whhT = ws + WHHT_OFF;
    const float* invd = ws + INVD_OFF;
    float* loss_part = ws + LOSS_OFF;
    float* imp = ws + IMP_OFF;

    int bid = blockIdx.x;
    int b = bid / 3, k = bid - 3 * b;
    int tid = threadIdx.x;

    __shared__ float Wdh_s[Hn][Fn + 1];      // 128x37
    __shared__ float Whist_s[Fn][Hn + 1];    // 36x129
    __shared__ float Wf_s[Fn][Fn + 1];       // 36x37, diag zeroed
    __shared__ float Wwc_s[Fn][F2n + 1];     // 36x73
    __shared__ float h_s[Hn];
    __shared__ float gates_s[G4];
    __shared__ float m_s[Fn], d_s[Fn], rt_s[Fn], tr_s[Fn], se_s[Fn];
    __shared__ float xh_s[Fn], xc_s[Fn], zh_s[Fn], alpha_s[Fn], gx_s[Fn];
    __shared__ float inp_s[F2n];
    __shared__ float bdh_s[Hn];
    __shared__ float bh_s[Fn], bf_s[Fn], bwc_s[Fn], wdxd_s[Fn], bdx_s[Fn];

    for (int i = tid; i < Hn * Fn; i += 256) Wdh_s[i / Fn][i % Fn] = W_dh[i];
    for (int i = tid; i < Fn * Hn; i += 256) Whist_s[i / Hn][i % Hn] = W_hist[i];
    for (int i = tid; i < Fn * Fn; i += 256) {
        int r = i / Fn, c = i - r * Fn;
        Wf_s[r][c] = (r == c) ? 0.f : W_feat[i];
    }
    for (int i = tid; i < Fn * F2n; i += 256) Wwc_s[i / F2n][i % F2n] = W_wc[i];
    if (tid < Hn) { bdh_s[tid] = b_dh[tid]; h_s[tid] = 0.f; }
    if (tid < Fn) {
        bh_s[tid] = b_hist[tid]; bf_s[tid] = b_feat[tid]; bwc_s[tid] = b_wc[tid];
        wdxd_s[tid] = W_dx[tid * (Fn + 1)]; bdx_s[tid] = b_dx[tid];
    }
    float c_reg = 0.f;                 // cell state for unit tid (tid<128)
    int j0 = 2 * tid;
    float bias0 = b_ih[j0] + b_hh[j0];
    float bias1 = b_ih[j0 + 1] + b_hh[j0 + 1];

    // wk[k] from softmax(W_comb)
    float w0 = W_comb[0], w1 = W_comb[1], w2 = W_comb[2];
    float mx = fmaxf(w0, fmaxf(w1, w2));
    float e0 = expf(w0 - mx), e1 = expf(w1 - mx), e2 = expf(w2 - mx);
    float wkk = ((k == 0) ? e0 : (k == 1) ? e1 : e2) / (e0 + e1 + e2);

    float loss_acc = 0.f;
    const float* base_m = data + (size_t)(b * 24 + 1) * Tn * Fn;
    const float* base_d = data + (size_t)(b * 24 + 2) * Tn * Fn;
    const float* base_r = data + (size_t)(b * 24 + 3 + 3 * k) * Tn * Fn;
    const float* base_t = data + (size_t)(b * 24 + 4 + 3 * k) * Tn * Fn;
    const float* base_s = data + (size_t)(b * 24 + 5 + 3 * k) * Tn * Fn;
    float* imp_b = imp + (size_t)(k * Bn + b) * Tn * Fn;

    __syncthreads();

    for (int t = 0; t < Tn; ++t) {
        if (tid < Fn) {
            m_s[tid]  = base_m[t * Fn + tid];
            d_s[tid]  = base_d[t * Fn + tid];
            rt_s[tid] = base_r[t * Fn + tid];
            tr_s[tid] = base_t[t * Fn + tid];
            se_s[tid] = base_s[t * Fn + tid];
        }
        __syncthreads();
        // gamma_h and h decay
        if (tid < Hn) {
            float acc = bdh_s[tid];
            #pragma unroll
            for (int f = 0; f < Fn; ++f) acc = fmaf(d_s[f], Wdh_s[tid][f], acc);
            h_s[tid] *= __expf(-fmaxf(acc, 0.f));
        }
        __syncthreads();
        // x_h, x_c, gamma_x
        if (tid < Fn) {
            float a0 = bh_s[tid], a1 = 0.f, a2 = 0.f, a3 = 0.f;
            #pragma unroll
            for (int hh = 0; hh < Hn; hh += 4) {
                a0 = fmaf(h_s[hh],     Whist_s[tid][hh],     a0);
                a1 = fmaf(h_s[hh + 1], Whist_s[tid][hh + 1], a1);
                a2 = fmaf(h_s[hh + 2], Whist_s[tid][hh + 2], a2);
                a3 = fmaf(h_s[hh + 3], Whist_s[tid][hh + 3], a3);
            }
            float xh = (a0 + a1) + (a2 + a3);
            xh_s[tid] = xh;
            float m = m_s[tid], rt = rt_s[tid];
            xc_s[tid] = m * rt + (1.f - m) * xh;
            gx_s[tid] = __expf(-fmaxf(fmaf(d_s[tid], wdxd_s[tid], bdx_s[tid]), 0.f));
        }
        __syncthreads();
        // z_h (threads 0..35) and alpha (threads 64..99, different wave -> parallel)
        if (tid < Fn) {
            float a = bf_s[tid];
            #pragma unroll
            for (int f = 0; f < Fn; ++f) a = fmaf(xc_s[f], Wf_s[tid][f], a);
            zh_s[tid] = a;
        } else if (tid >= 64 && tid < 64 + Fn) {
            int g = tid - 64;
            float a = bwc_s[g];
            #pragma unroll
            for (int f = 0; f < Fn; ++f) a = fmaf(gx_s[f], Wwc_s[g][f], a);
            #pragma unroll
            for (int f = 0; f < Fn; ++f) a = fmaf(m_s[f], Wwc_s[g][Fn + f], a);
            alpha_s[g] = a;
        }
        __syncthreads();
        // c_h, c_c, loss terms, impute partial
        if (tid < Fn) {
            float al = alpha_s[tid], zh = zh_s[tid], xh = xh_s[tid];
            float ch = al * zh + (1.f - al) * xh;
            float m = m_s[tid], rt = rt_s[tid];
            float cc = m * rt + (1.f - m) * ch;
            inp_s[tid] = cc;
            inp_s[Fn + tid] = m;
            loss_acc = fmaf((fabsf(rt - xh) + fabsf(rt - zh) + fabsf(rt - ch)) * m,
                            invd[t], loss_acc);
            imp_b[t * Fn + tid] = cc + se_s[tid] + tr_s[tid];
        }
        __syncthreads();
        // gates: thread owns rows j0, j0+1 (coalesced float2 from transposed weights)
        {
            float g0 = bias0, g1 = bias1;
            const float* wi = wihT + j0;
            #pragma unroll 8
            for (int kk = 0; kk < F2n; ++kk) {
                float x = inp_s[kk];
                float2 w = *(const float2*)(wi + kk * G4);
                g0 = fmaf(x, w.x, g0); g1 = fmaf(x, w.y, g1);
            }
            const float* wh = whhT + j0;
            #pragma unroll 8
            for (int hh = 0; hh < Hn; ++hh) {
                float x = h_s[hh];
                float2 w = *(const float2*)(wh + hh * G4);
                g0 = fmaf(x, w.x, g0); g1 = fmaf(x, w.y, g1);
            }
            gates_s[j0] = g0; gates_s[j0 + 1] = g1;
        }
        __syncthreads();
        // LSTM update
        if (tid < Hn) {
            float ig = gates_s[tid], fg = gates_s[Hn + tid];
            float gg = gates_s[2 * Hn + tid], og = gates_s[3 * Hn + tid];
            c_reg = sigmoid_f(fg) * c_reg + sigmoid_f(ig) * tanh_f(gg);
            h_s[tid] = sigmoid_f(og) * tanh_f(c_reg);
        }
        __syncthreads();
    }

    // per-block loss partial (fixed-order reduce -> deterministic)
    if (tid < Fn) gates_s[tid] = loss_acc;
    __syncthreads();
    if (tid == 0) {
        float s = 0.f;
        for (int i = 0; i < Fn; ++i) s += gates_s[i];
        loss_part[bid] = s * wkk;
    }
}

// ---------------- k-reduction of imputations ----------------
__global__ void impute_reduce(const float* __restrict__ ws,
                              const float* __restrict__ W_comb,
                              float* __restrict__ out) {
    int idx = blockIdx.x * 256 + threadIdx.x;   // < BTFn exactly
    float w0 = W_comb[0], w1 = W_comb[1], w2 = W_comb[2];
    float mx = fmaxf(w0, fmaxf(w1, w2));
    float e0 = expf(w0 - mx), e1 = expf(w1 - mx), e2 = expf(w2 - mx);
    float inv = 1.f / (e0 + e1 + e2);
    const float* imp = ws + IMP_OFF;
    out[1 + idx] = (e0 * imp[idx] + e1 * imp[BTFn + idx] + e2 * imp[2 * BTFn + idx]) * inv;
}

// ---------------- final loss ----------------
__global__ void loss_final(const float* __restrict__ ws,
                           const float* __restrict__ W_comb,
                           float* __restrict__ out) {
    int tid = threadIdx.x;
    __shared__ float red[256];
    const float* lp = ws + LOSS_OFF;
    float s = lp[tid];
    if (tid < 128) s += lp[tid + 256];
    red[tid] = s;
    __syncthreads();
    for (int off = 128; off > 0; off >>= 1) {
        if (tid < off) red[tid] += red[tid + off];
        __syncthreads();
    }
    if (tid == 0) {
        float w0 = W_comb[0], w1 = W_comb[1], w2 = W_comb[2];
        float mx = fmaxf(w0, fmaxf(w1, w2));
        float e0 = expf(w0 - mx), e1 = expf(w1 - mx), e2 = expf(w2 - mx);
        float inv = 1.f / (e0 + e1 + e2);
        float wk0 = e0 * inv, wk1 = e1 * inv, wk2 = e2 * inv;
        float reg = 0.1f * (wk0 * (1.f / 24.f) + wk1 * (1.f / 168.f) + wk2 * (1.f / 720.f));
        out[0] = red[0] + (float)Tn * reg;
    }
}

extern "C" void kernel_launch(void* const* d_in, const int* in_sizes, int n_in,
                              void* d_out, int out_size, void* d_ws, size_t ws_size,
                              hipStream_t stream) {
    const float* data   = (const float*)d_in[0];
    const float* W_dh   = (const float*)d_in[1];
    const float* b_dh   = (const float*)d_in[2];
    const float* W_dx   = (const float*)d_in[3];
    const float* b_dx   = (const float*)d_in[4];
    const float* W_hist = (const float*)d_in[5];
    const float* b_hist = (const float*)d_in[6];
    const float* W_feat = (const float*)d_in[7];
    const float* b_feat = (const float*)d_in[8];
    const float* W_wc   = (const float*)d_in[9];
    const float* b_wc   = (const float*)d_in[10];
    const float* W_ih   = (const float*)d_in[11];
    const float* W_hh   = (const float*)d_in[12];
    const float* b_ih   = (const float*)d_in[13];
    const float* b_hh   = (const float*)d_in[14];
    const float* W_comb = (const float*)d_in[15];
    float* ws = (float*)d_ws;
    float* out = (float*)d_out;

    hipLaunchKernelGGL(prep_kernel, dim3(Tn), dim3(256), 0, stream, data, W_ih, W_hh, ws);
    hipLaunchKernelGGL(rits_main, dim3(Bn * 3), dim3(256), 0, stream,
                       data, W_dh, b_dh, W_dx, b_dx, W_hist, b_hist,
                       W_feat, b_feat, W_wc, b_wc, b_ih, b_hh, W_comb, ws);
    hipLaunchKernelGGL(impute_reduce, dim3(BTFn / 256), dim3(256), 0, stream, ws, W_comb, out);
    hipLaunchKernelGGL(loss_final, dim3(1), dim3(256), 0, stream, ws, W_comb, out);
}